// Round 1
// baseline (2590.102 us; speedup 1.0000x reference)
//
#include <hip/hip_runtime.h>

#define C 128

// ---------------- degree count (atomics over 1.6M edges) ----------------
__global__ void k_degree(const int* __restrict__ col, int* __restrict__ cnt, int E) {
  int e = blockIdx.x * blockDim.x + threadIdx.x;
  if (e < E) atomicAdd(&cnt[col[e]], 1);
}

// ---------------- single-block scan: deg -> dis, indptr, cursor --------
__global__ void k_scan(const int* __restrict__ cnt, float* __restrict__ dis,
                       int* __restrict__ indptr, int* __restrict__ cursor, int N) {
  __shared__ int sb[1024];
  int t = threadIdx.x;
  int chunk = (N + 1023) >> 10;
  int lo = t * chunk, hi = min(lo + chunk, N);
  int sum = 0;
  for (int i = lo; i < hi; ++i) sum += cnt[i];
  sb[t] = sum;
  __syncthreads();
  for (int off = 1; off < 1024; off <<= 1) {
    int v = (t >= off) ? sb[t - off] : 0;
    __syncthreads();
    sb[t] += v;
    __syncthreads();
  }
  int run = sb[t] - sum;  // exclusive prefix
  for (int i = lo; i < hi; ++i) {
    indptr[i] = run; cursor[i] = run;
    dis[i] = rsqrtf((float)(cnt[i] + 1));  // +1 self loop
    run += cnt[i];
  }
  if (lo < N && hi == N) indptr[N] = run;
}

// ---------------- CSR fill (dst-sorted src + norm) ----------------------
__global__ void k_csrfill(const int* __restrict__ row, const int* __restrict__ col,
                          const float* __restrict__ dis, int* __restrict__ cursor,
                          int* __restrict__ esrc, float* __restrict__ enorm, int E) {
  int e = blockIdx.x * blockDim.x + threadIdx.x;
  if (e >= E) return;
  int r = row[e], c = col[e];
  int pos = atomicAdd(&cursor[c], 1);
  esrc[pos] = r;
  enorm[pos] = dis[r] * dis[c];
}

// ---------------- aggregation: agg[v] = sum norm*h[src] + dis^2*h[v] ----
// one wave per node, lane covers 2 channels (float2, coalesced 512B/row)
__global__ __launch_bounds__(256)
void k_agg(const float* __restrict__ h, const int* __restrict__ indptr,
           const int* __restrict__ esrc, const float* __restrict__ enorm,
           const float* __restrict__ dis, float* __restrict__ agg, int N) {
  int w = (blockIdx.x * 256 + threadIdx.x) >> 6;
  int lane = threadIdx.x & 63;
  if (w >= N) return;
  int s = indptr[w], e = indptr[w + 1];
  float ax = 0.f, ay = 0.f;
  int i = s;
  for (; i + 2 <= e; i += 2) {  // 2-edge unroll for ILP
    int s0 = esrc[i], s1 = esrc[i + 1];
    float n0 = enorm[i], n1 = enorm[i + 1];
    float2 h0 = *(const float2*)(h + (size_t)s0 * C + lane * 2);
    float2 h1 = *(const float2*)(h + (size_t)s1 * C + lane * 2);
    ax += n0 * h0.x + n1 * h1.x;
    ay += n0 * h0.y + n1 * h1.y;
  }
  if (i < e) {
    int s0 = esrc[i]; float n0 = enorm[i];
    float2 h0 = *(const float2*)(h + (size_t)s0 * C + lane * 2);
    ax += n0 * h0.x; ay += n0 * h0.y;
  }
  float dv = dis[w];
  float2 hs = *(const float2*)(h + (size_t)w * C + lane * 2);
  ax += dv * dv * hs.x; ay += dv * dv * hs.y;
  float2 o; o.x = ax; o.y = ay;
  *(float2*)(agg + (size_t)w * C + lane * 2) = o;
}

// ---------------- GEMM: out[M,128] = op(A[M,128] @ W[128,128]) ----------
// 64-row tile, A transposed in LDS (32KB) + W in 2x 64-row halves (32KB)
// thread = 4 rows x 8 cols. Fused bias/skip/relu epilogue.
__global__ __launch_bounds__(256, 2)
void k_gemm(const float* __restrict__ A, const float* __restrict__ W,
            const float* __restrict__ bias, const float* __restrict__ skip,
            float* __restrict__ out, int M, int relu) {
  __shared__ float At[C][64];   // [k][r]
  __shared__ float Wl[64][C];   // [k-half][c]
  int t = threadIdx.x;
  int r0 = blockIdx.x * 64;
  {
    int rl = t >> 2, p = t & 3;
    int r = r0 + rl;
    const float* Ar = A + (size_t)r * C + p * 32;
#pragma unroll
    for (int i = 0; i < 8; ++i) {
      float4 v = make_float4(0.f, 0.f, 0.f, 0.f);
      if (r < M) v = *(const float4*)(Ar + 4 * i);
      int ch = p * 32 + 4 * i;
      At[ch + 0][rl] = v.x; At[ch + 1][rl] = v.y;
      At[ch + 2][rl] = v.z; At[ch + 3][rl] = v.w;
    }
  }
  int cg = t & 15, rg = t >> 4;
  float acc[4][8];
#pragma unroll
  for (int i = 0; i < 4; ++i)
#pragma unroll
    for (int j = 0; j < 8; ++j) acc[i][j] = 0.f;

  for (int half = 0; half < 2; ++half) {
    __syncthreads();
    {
      const float* Wp = W + half * 64 * C;
#pragma unroll
      for (int i = 0; i < 8; ++i) {
        int idx = (i * 256 + t) * 4;
        *(float4*)((float*)Wl + idx) = *(const float4*)(Wp + idx);
      }
    }
    __syncthreads();
#pragma unroll 4
    for (int kk = 0; kk < 64; ++kk) {
      float4 a = *(const float4*)&At[half * 64 + kk][rg * 4];
      float4 w0 = *(const float4*)&Wl[kk][cg * 8];
      float4 w1 = *(const float4*)&Wl[kk][cg * 8 + 4];
      float av[4] = {a.x, a.y, a.z, a.w};
      float wv[8] = {w0.x, w0.y, w0.z, w0.w, w1.x, w1.y, w1.z, w1.w};
#pragma unroll
      for (int i = 0; i < 4; ++i)
#pragma unroll
        for (int j = 0; j < 8; ++j) acc[i][j] = fmaf(av[i], wv[j], acc[i][j]);
    }
  }
  int c0 = cg * 8;
  float bv[8];
#pragma unroll
  for (int j = 0; j < 8; ++j) bv[j] = bias ? bias[c0 + j] : 0.f;
#pragma unroll
  for (int i = 0; i < 4; ++i) {
    int r = r0 + rg * 4 + i;
    if (r >= M) continue;
    float o[8];
#pragma unroll
    for (int j = 0; j < 8; ++j) {
      float v = acc[i][j] + bv[j];
      if (skip) v += skip[(size_t)r * C + c0 + j];
      if (relu) v = fmaxf(v, 0.f);
      o[j] = v;
    }
    *(float4*)(out + (size_t)r * C + c0) = make_float4(o[0], o[1], o[2], o[3]);
    *(float4*)(out + (size_t)r * C + c0 + 4) = make_float4(o[4], o[5], o[6], o[7]);
  }
}

// ---------------- fused edge MLP ----------------------------------------
// 64 edges/block. e1 = relu(P[row]+Q[col]) built transposed in LDS, then
// fc1 GEMM (same tiling as k_gemm), fused relu+b1 and fc2 dot + reduce.
__global__ __launch_bounds__(256, 2)
void k_edge(const float* __restrict__ P, const float* __restrict__ Q,
            const int* __restrict__ row, const int* __restrict__ col,
            const float* __restrict__ W1, const float* __restrict__ b1,
            const float* __restrict__ w2, const float* __restrict__ b2,
            float* __restrict__ out, int E) {
  __shared__ float Et[C][64];   // e1 transposed [k][edge]
  __shared__ float Wl[64][C];
  int t = threadIdx.x;
  int e0 = blockIdx.x * 64;
  {
    int el = t >> 2, p = t & 3;
    int e = min(e0 + el, E - 1);
    int r = row[e], c = col[e];
    const float* Pp = P + (size_t)r * C + p * 32;
    const float* Qp = Q + (size_t)c * C + p * 32;
#pragma unroll
    for (int i = 0; i < 8; ++i) {
      float4 a = *(const float4*)(Pp + 4 * i);
      float4 b = *(const float4*)(Qp + 4 * i);
      int ch = p * 32 + 4 * i;
      Et[ch + 0][el] = fmaxf(a.x + b.x, 0.f);
      Et[ch + 1][el] = fmaxf(a.y + b.y, 0.f);
      Et[ch + 2][el] = fmaxf(a.z + b.z, 0.f);
      Et[ch + 3][el] = fmaxf(a.w + b.w, 0.f);
    }
  }
  int cg = t & 15, rg = t >> 4;
  float acc[4][8];
#pragma unroll
  for (int i = 0; i < 4; ++i)
#pragma unroll
    for (int j = 0; j < 8; ++j) acc[i][j] = 0.f;

  for (int half = 0; half < 2; ++half) {
    __syncthreads();
    {
      const float* Wp = W1 + half * 64 * C;
#pragma unroll
      for (int i = 0; i < 8; ++i) {
        int idx = (i * 256 + t) * 4;
        *(float4*)((float*)Wl + idx) = *(const float4*)(Wp + idx);
      }
    }
    __syncthreads();
#pragma unroll 4
    for (int kk = 0; kk < 64; ++kk) {
      float4 a = *(const float4*)&Et[half * 64 + kk][rg * 4];
      float4 w0 = *(const float4*)&Wl[kk][cg * 8];
      float4 w1 = *(const float4*)&Wl[kk][cg * 8 + 4];
      float av[4] = {a.x, a.y, a.z, a.w};
      float wv[8] = {w0.x, w0.y, w0.z, w0.w, w1.x, w1.y, w1.z, w1.w};
#pragma unroll
      for (int i = 0; i < 4; ++i)
#pragma unroll
        for (int j = 0; j < 8; ++j) acc[i][j] = fmaf(av[i], wv[j], acc[i][j]);
    }
  }
  // epilogue: e2 = relu(acc + b1), out = e2 . w2 + b2
  int c0 = cg * 8;
  float b1v[8], w2v[8];
#pragma unroll
  for (int j = 0; j < 8; ++j) { b1v[j] = b1[c0 + j]; w2v[j] = w2[c0 + j]; }
  float part[4];
#pragma unroll
  for (int i = 0; i < 4; ++i) {
    float s = 0.f;
#pragma unroll
    for (int j = 0; j < 8; ++j) {
      float e2 = fmaxf(acc[i][j] + b1v[j], 0.f);
      s += e2 * w2v[j];
    }
    part[i] = s;
  }
#pragma unroll
  for (int off = 1; off < 16; off <<= 1) {
#pragma unroll
    for (int i = 0; i < 4; ++i) part[i] += __shfl_xor(part[i], off, 64);
  }
  if (cg == 0) {
    float bb = b2[0];
#pragma unroll
    for (int i = 0; i < 4; ++i) {
      int e = e0 + rg * 4 + i;
      if (e < E) out[e] = part[i] + bb;
    }
  }
}

// ---------------- host ---------------------------------------------------
extern "C" void kernel_launch(void* const* d_in, const int* in_sizes, int n_in,
                              void* d_out, int out_size, void* d_ws, size_t ws_size,
                              hipStream_t stream) {
  const float* x       = (const float*)d_in[0];
  const int*   ei      = (const int*)d_in[1];
  const float* convs_W = (const float*)d_in[2];
  const float* convs_b = (const float*)d_in[3];
  const float* fc0_W   = (const float*)d_in[4];
  const float* fc0_b   = (const float*)d_in[5];
  const float* fc1_W   = (const float*)d_in[6];
  const float* fc1_b   = (const float*)d_in[7];
  const float* fc2_W   = (const float*)d_in[8];
  const float* fc2_b   = (const float*)d_in[9];
  float* out = (float*)d_out;

  const int N = in_sizes[0] / C;        // 50000
  const int E = in_sizes[1] / 2;        // 1600000
  const int L = in_sizes[2] / (C * C);  // 8
  const int* row = ei;
  const int* col = ei + E;

  char* wp = (char*)d_ws;
  auto carve = [&](size_t bytes) {
    char* p = wp; wp += (bytes + 255) & ~(size_t)255; return p;
  };
  int*   cnt    = (int*)carve((size_t)N * 4);
  int*   indptr = (int*)carve((size_t)(N + 1) * 4);
  int*   cursor = (int*)carve((size_t)N * 4);
  float* dis    = (float*)carve((size_t)N * 4);
  int*   esrc   = (int*)carve((size_t)E * 4);
  float* enorm  = (float*)carve((size_t)E * 4);
  float* big0   = (float*)carve((size_t)N * C * 4);
  float* big1   = (float*)carve((size_t)N * C * 4);
  float* big2   = (float*)carve((size_t)N * C * 4);
  // total ~90.6 MB of d_ws

  hipMemsetAsync(cnt, 0, (size_t)N * 4, stream);
  k_degree<<<(E + 255) / 256, 256, 0, stream>>>(col, cnt, E);
  k_scan<<<1, 1024, 0, stream>>>(cnt, dis, indptr, cursor, N);
  k_csrfill<<<(E + 255) / 256, 256, 0, stream>>>(row, col, dis, cursor, esrc, enorm, E);

  int aggBlocks  = (N * 64 + 255) / 256;
  int gemmBlocks = (N + 63) / 64;

  // layer 0 (no skip)
  k_agg<<<aggBlocks, 256, 0, stream>>>(x, indptr, esrc, enorm, dis, big1, N);
  k_gemm<<<gemmBlocks, 256, 0, stream>>>(big1, convs_W, convs_b, nullptr, big0, N, 1);
  float* hcur = big0; float* fA = big1; float* fB = big2;
  for (int l = 1; l < L; ++l) {
    k_agg<<<aggBlocks, 256, 0, stream>>>(hcur, indptr, esrc, enorm, dis, fA, N);
    k_gemm<<<gemmBlocks, 256, 0, stream>>>(fA, convs_W + (size_t)l * C * C,
                                           convs_b + (size_t)l * C, hcur, fB, N, 1);
    float* tmp = hcur; hcur = fB; fB = tmp;
  }
  // edge MLP: P = h@fc0_W[:128], Q = h@fc0_W[128:] + b0 (bias folded)
  float* Pm = fA; float* Qm = fB;
  k_gemm<<<gemmBlocks, 256, 0, stream>>>(hcur, fc0_W, nullptr, nullptr, Pm, N, 0);
  k_gemm<<<gemmBlocks, 256, 0, stream>>>(hcur, fc0_W + C * C, fc0_b, nullptr, Qm, N, 0);
  k_edge<<<(E + 63) / 64, 256, 0, stream>>>(Pm, Qm, row, col, fc1_W, fc1_b,
                                            fc2_W, fc2_b, out, E);
}

// Round 3
// 2151.409 us; speedup vs baseline: 1.2039x; 1.2039x over previous
//
#include <hip/hip_runtime.h>

#define C 128

typedef __attribute__((ext_vector_type(8))) short short8v;
typedef __attribute__((ext_vector_type(4))) float float4v;

__device__ __forceinline__ ushort f2bf(float f) {
  union { float f; uint u; } v; v.f = f;
  uint u = v.u;
  return (ushort)((u + 0x7FFF + ((u >> 16) & 1)) >> 16);  // RNE
}
__device__ __forceinline__ float bf2f(ushort s) {
  union { uint u; float f; } v; v.u = ((uint)s) << 16; return v.f;
}

// ---------------- degree count (atomics over 1.6M edges) ----------------
__global__ void k_degree(const int* __restrict__ col, int* __restrict__ cnt, int E) {
  int e = blockIdx.x * blockDim.x + threadIdx.x;
  if (e < E) atomicAdd(&cnt[col[e]], 1);
}

// ---------------- single-block scan: deg -> dis, indptr, cursor --------
__global__ void k_scan(const int* __restrict__ cnt, float* __restrict__ dis,
                       int* __restrict__ indptr, int* __restrict__ cursor, int N) {
  __shared__ int sb[1024];
  int t = threadIdx.x;
  int chunk = (N + 1023) >> 10;
  int lo = t * chunk, hi = min(lo + chunk, N);
  int sum = 0;
  for (int i = lo; i < hi; ++i) sum += cnt[i];
  sb[t] = sum;
  __syncthreads();
  for (int off = 1; off < 1024; off <<= 1) {
    int v = (t >= off) ? sb[t - off] : 0;
    __syncthreads();
    sb[t] += v;
    __syncthreads();
  }
  int run = sb[t] - sum;  // exclusive prefix
  for (int i = lo; i < hi; ++i) {
    indptr[i] = run; cursor[i] = run;
    dis[i] = rsqrtf((float)(cnt[i] + 1));  // +1 self loop
    run += cnt[i];
  }
  if (lo < N && hi == N) indptr[N] = run;
}

// ---------------- CSR fill (dst-sorted src + norm) ----------------------
__global__ void k_csrfill(const int* __restrict__ row, const int* __restrict__ col,
                          const float* __restrict__ dis, int* __restrict__ cursor,
                          int* __restrict__ esrc, float* __restrict__ enorm, int E) {
  int e = blockIdx.x * blockDim.x + threadIdx.x;
  if (e >= E) return;
  int r = row[e], c = col[e];
  int pos = atomicAdd(&cursor[c], 1);
  esrc[pos] = r;
  enorm[pos] = dis[r] * dis[c];
}

// ---------------- W1^T -> bf16 (once) -----------------------------------
__global__ void k_prepw(const float* __restrict__ W1, ushort* __restrict__ W1t) {
  int idx = blockIdx.x * 256 + threadIdx.x;  // 16384
  int n = idx >> 7, k = idx & 127;
  W1t[idx] = f2bf(W1[k * C + n]);
}

// ---------------- aggregation: agg[v] = sum norm*h[src] + dis^2*h[v] ----
__global__ __launch_bounds__(256)
void k_agg(const float* __restrict__ h, const int* __restrict__ indptr,
           const int* __restrict__ esrc, const float* __restrict__ enorm,
           const float* __restrict__ dis, float* __restrict__ agg, int N) {
  int w = (blockIdx.x * 256 + threadIdx.x) >> 6;
  int lane = threadIdx.x & 63;
  if (w >= N) return;
  int s = indptr[w], e = indptr[w + 1];
  float ax = 0.f, ay = 0.f;
  int i = s;
  for (; i + 2 <= e; i += 2) {
    int s0 = esrc[i], s1 = esrc[i + 1];
    float n0 = enorm[i], n1 = enorm[i + 1];
    float2 h0 = *(const float2*)(h + (size_t)s0 * C + lane * 2);
    float2 h1 = *(const float2*)(h + (size_t)s1 * C + lane * 2);
    ax += n0 * h0.x + n1 * h1.x;
    ay += n0 * h0.y + n1 * h1.y;
  }
  if (i < e) {
    int s0 = esrc[i]; float n0 = enorm[i];
    float2 h0 = *(const float2*)(h + (size_t)s0 * C + lane * 2);
    ax += n0 * h0.x; ay += n0 * h0.y;
  }
  float dv = dis[w];
  float2 hs = *(const float2*)(h + (size_t)w * C + lane * 2);
  ax += dv * dv * hs.x; ay += dv * dv * hs.y;
  float2 o; o.x = ax; o.y = ay;
  *(float2*)(agg + (size_t)w * C + lane * 2) = o;
}

// ---------------- GEMM: out[M,128] = op(A[M,128] @ W[128,128]) ----------
__global__ __launch_bounds__(256, 2)
void k_gemm(const float* __restrict__ A, const float* __restrict__ W,
            const float* __restrict__ bias, const float* __restrict__ skip,
            float* __restrict__ out, int M, int relu) {
  __shared__ float At[C][64];   // [k][r]
  __shared__ float Wl[64][C];   // [k-half][c]
  int t = threadIdx.x;
  int r0 = blockIdx.x * 64;
  {
    int rl = t >> 2, p = t & 3;
    int r = r0 + rl;
    const float* Ar = A + (size_t)r * C + p * 32;
#pragma unroll
    for (int i = 0; i < 8; ++i) {
      float4 v = make_float4(0.f, 0.f, 0.f, 0.f);
      if (r < M) v = *(const float4*)(Ar + 4 * i);
      int ch = p * 32 + 4 * i;
      At[ch + 0][rl] = v.x; At[ch + 1][rl] = v.y;
      At[ch + 2][rl] = v.z; At[ch + 3][rl] = v.w;
    }
  }
  int cg = t & 15, rg = t >> 4;
  float acc[4][8];
#pragma unroll
  for (int i = 0; i < 4; ++i)
#pragma unroll
    for (int j = 0; j < 8; ++j) acc[i][j] = 0.f;

  for (int half = 0; half < 2; ++half) {
    __syncthreads();
    {
      const float* Wp = W + half * 64 * C;
#pragma unroll
      for (int i = 0; i < 8; ++i) {
        int idx = (i * 256 + t) * 4;
        *(float4*)((float*)Wl + idx) = *(const float4*)(Wp + idx);
      }
    }
    __syncthreads();
#pragma unroll 4
    for (int kk = 0; kk < 64; ++kk) {
      float4 a = *(const float4*)&At[half * 64 + kk][rg * 4];
      float4 w0 = *(const float4*)&Wl[kk][cg * 8];
      float4 w1 = *(const float4*)&Wl[kk][cg * 8 + 4];
      float av[4] = {a.x, a.y, a.z, a.w};
      float wv[8] = {w0.x, w0.y, w0.z, w0.w, w1.x, w1.y, w1.z, w1.w};
#pragma unroll
      for (int i = 0; i < 4; ++i)
#pragma unroll
        for (int j = 0; j < 8; ++j) acc[i][j] = fmaf(av[i], wv[j], acc[i][j]);
    }
  }
  int c0 = cg * 8;
  float bv[8];
#pragma unroll
  for (int j = 0; j < 8; ++j) bv[j] = bias ? bias[c0 + j] : 0.f;
#pragma unroll
  for (int i = 0; i < 4; ++i) {
    int r = r0 + rg * 4 + i;
    if (r >= M) continue;
    float o[8];
#pragma unroll
    for (int j = 0; j < 8; ++j) {
      float v = acc[i][j] + bv[j];
      if (skip) v += skip[(size_t)r * C + c0 + j];
      if (relu) v = fmaxf(v, 0.f);
      o[j] = v;
    }
    *(float4*)(out + (size_t)r * C + c0) = make_float4(o[0], o[1], o[2], o[3]);
    *(float4*)(out + (size_t)r * C + c0 + 4) = make_float4(o[4], o[5], o[6], o[7]);
  }
}

// ---------------- fused edge MLP, MFMA fc1, hi/lo split e1 ---------------
// 64 edges/block. e1 = relu(P[row]+Q[col]) computed fp32, stored as bf16
// hi + lo pair in LDS (XOR chunk-swizzled, no padding). W1^T bf16 staged
// swizzled. acc = (e1_hi + e1_lo) @ W1  (2 MFMAs per tile) -> e1 error is
// ~2^-17 relative; only W1-bf16 rounding remains. Total LDS exactly 64KB.
__device__ __forceinline__ short* swz(short* base, int row, int chunk) {
  // row stride 128 shorts (256B); 16 chunks of 8 shorts (16B) per row
  return base + row * 128 + ((chunk ^ (row & 15)) << 3);
}

__global__ __launch_bounds__(256, 2)
void k_edge(const float* __restrict__ P, const float* __restrict__ Q,
            const int* __restrict__ row, const int* __restrict__ col,
            const ushort* __restrict__ W1t, const float* __restrict__ b1,
            const float* __restrict__ w2, const float* __restrict__ b2,
            float* __restrict__ out, int E) {
  __shared__ __align__(16) short EtH[64 * 128];
  __shared__ __align__(16) short EtL[64 * 128];
  __shared__ __align__(16) short Wl[128 * 128];
  int t = threadIdx.x;
  int e0 = blockIdx.x * 64;
  // stage e1 (fp32) -> hi/lo bf16 LDS, swizzled
  {
    int el = t >> 2, p = t & 3;
    int e = e0 + el;
    if (e >= E) e = E - 1;
    int r = row[e], c = col[e];
    const float* Pp = P + (size_t)r * C + p * 32;
    const float* Qp = Q + (size_t)c * C + p * 32;
#pragma unroll
    for (int i = 0; i < 4; ++i) {  // 8 channels per iter
      float4 a0 = *(const float4*)(Pp + 8 * i);
      float4 a1 = *(const float4*)(Pp + 8 * i + 4);
      float4 b0 = *(const float4*)(Qp + 8 * i);
      float4 b1v4 = *(const float4*)(Qp + 8 * i + 4);
      float v[8] = {a0.x + b0.x, a0.y + b0.y, a0.z + b0.z, a0.w + b0.w,
                    a1.x + b1v4.x, a1.y + b1v4.y, a1.z + b1v4.z, a1.w + b1v4.w};
      short8v hi, lo;
#pragma unroll
      for (int j = 0; j < 8; ++j) {
        float f = fmaxf(v[j], 0.f);
        ushort h = f2bf(f);
        hi[j] = (short)h;
        lo[j] = (short)f2bf(f - bf2f(h));
      }
      *(short8v*)swz(EtH, el, p * 4 + i) = hi;
      *(short8v*)swz(EtL, el, p * 4 + i) = lo;
    }
  }
  // stage W1^T -> LDS swizzled (global stays fully coalesced)
  {
#pragma unroll
    for (int i = 0; i < 8; ++i) {
      int g = i * 256 + t;           // chunk id 0..2047
      int r = g >> 4, c = g & 15;
      short8v w = *(const short8v*)(W1t + g * 8);
      *(short8v*)swz(Wl, r, c) = w;
    }
  }
  __syncthreads();

  int w = t >> 6, lane = t & 63;
  int m0 = w * 16;
  int lm = lane & 15, lq = lane >> 4;
  float4v acc[8];
#pragma unroll
  for (int j = 0; j < 8; ++j) acc[j] = (float4v){0.f, 0.f, 0.f, 0.f};

#pragma unroll
  for (int kk = 0; kk < 4; ++kk) {
    int ch = kk * 4 + lq;            // 16B chunk index along K
    short8v ah = *(const short8v*)swz(EtH, m0 + lm, ch);
    short8v al = *(const short8v*)swz(EtL, m0 + lm, ch);
#pragma unroll
    for (int j = 0; j < 8; ++j) {
      short8v b = *(const short8v*)swz(Wl, j * 16 + lm, ch);
      acc[j] = __builtin_amdgcn_mfma_f32_16x16x32_bf16(ah, b, acc[j], 0, 0, 0);
      acc[j] = __builtin_amdgcn_mfma_f32_16x16x32_bf16(al, b, acc[j], 0, 0, 0);
    }
  }

  // epilogue: e2 = relu(acc + b1), out = e2 . w2 + b2
  float partv[4] = {0.f, 0.f, 0.f, 0.f};
#pragma unroll
  for (int j = 0; j < 8; ++j) {
    int n = j * 16 + lm;
    float b1v = b1[n], w2v = w2[n];
#pragma unroll
    for (int r = 0; r < 4; ++r) {
      float e2 = fmaxf(acc[j][r] + b1v, 0.f);
      partv[r] = fmaf(e2, w2v, partv[r]);
    }
  }
#pragma unroll
  for (int off = 1; off < 16; off <<= 1) {
#pragma unroll
    for (int r = 0; r < 4; ++r) partv[r] += __shfl_xor(partv[r], off, 64);
  }
  if (lm == 0) {
    float bb = b2[0];
#pragma unroll
    for (int r = 0; r < 4; ++r) {
      int e = e0 + m0 + lq * 4 + r;  // D row = lq*4 + r
      if (e < E) out[e] = partv[r] + bb;
    }
  }
}

// ---------------- host ---------------------------------------------------
extern "C" void kernel_launch(void* const* d_in, const int* in_sizes, int n_in,
                              void* d_out, int out_size, void* d_ws, size_t ws_size,
                              hipStream_t stream) {
  const float* x       = (const float*)d_in[0];
  const int*   ei      = (const int*)d_in[1];
  const float* convs_W = (const float*)d_in[2];
  const float* convs_b = (const float*)d_in[3];
  const float* fc0_W   = (const float*)d_in[4];
  const float* fc0_b   = (const float*)d_in[5];
  const float* fc1_W   = (const float*)d_in[6];
  const float* fc1_b   = (const float*)d_in[7];
  const float* fc2_W   = (const float*)d_in[8];
  const float* fc2_b   = (const float*)d_in[9];
  float* out = (float*)d_out;

  const int N = in_sizes[0] / C;        // 50000
  const int E = in_sizes[1] / 2;        // 1600000
  const int L = in_sizes[2] / (C * C);  // 8
  const int* row = ei;
  const int* col = ei + E;

  char* wp = (char*)d_ws;
  auto carve = [&](size_t bytes) {
    char* p = wp; wp += (bytes + 255) & ~(size_t)255; return p;
  };
  int*    cnt    = (int*)carve((size_t)N * 4);
  int*    indptr = (int*)carve((size_t)(N + 1) * 4);
  int*    cursor = (int*)carve((size_t)N * 4);
  float*  dis    = (float*)carve((size_t)N * 4);
  int*    esrc   = (int*)carve((size_t)E * 4);
  float*  enorm  = (float*)carve((size_t)E * 4);
  ushort* W1t    = (ushort*)carve((size_t)C * C * 2);
  float*  big0   = (float*)carve((size_t)N * C * 4);
  float*  big1   = (float*)carve((size_t)N * C * 4);
  float*  big2   = (float*)carve((size_t)N * C * 4);

  hipMemsetAsync(cnt, 0, (size_t)N * 4, stream);
  k_degree<<<(E + 255) / 256, 256, 0, stream>>>(col, cnt, E);
  k_scan<<<1, 1024, 0, stream>>>(cnt, dis, indptr, cursor, N);
  k_csrfill<<<(E + 255) / 256, 256, 0, stream>>>(row, col, dis, cursor, esrc, enorm, E);
  k_prepw<<<C * C / 256, 256, 0, stream>>>(fc1_W, W1t);

  int aggBlocks  = (N * 64 + 255) / 256;
  int gemmBlocks = (N + 63) / 64;

  // layer 0 (no skip)
  k_agg<<<aggBlocks, 256, 0, stream>>>(x, indptr, esrc, enorm, dis, big1, N);
  k_gemm<<<gemmBlocks, 256, 0, stream>>>(big1, convs_W, convs_b, nullptr, big0, N, 1);
  float* hcur = big0; float* fA = big1; float* fB = big2;
  for (int l = 1; l < L; ++l) {
    k_agg<<<aggBlocks, 256, 0, stream>>>(hcur, indptr, esrc, enorm, dis, fA, N);
    k_gemm<<<gemmBlocks, 256, 0, stream>>>(fA, convs_W + (size_t)l * C * C,
                                           convs_b + (size_t)l * C, hcur, fB, N, 1);
    float* tmp = hcur; hcur = fB; fB = tmp;
  }
  // edge MLP: P = h@fc0_W[:128], Q = h@fc0_W[128:] + b0 (bias folded) — fp32 out
  float* Pm = fA; float* Qm = fB;
  k_gemm<<<gemmBlocks, 256, 0, stream>>>(hcur, fc0_W, nullptr, nullptr, Pm, N, 0);
  k_gemm<<<gemmBlocks, 256, 0, stream>>>(hcur, fc0_W + C * C, fc0_b, nullptr, Qm, N, 0);
  k_edge<<<(E + 63) / 64, 256, 0, stream>>>(Pm, Qm, row, col, W1t, fc1_b,
                                            fc2_W, fc2_b, out, E);
}

// Round 4
// 1984.105 us; speedup vs baseline: 1.3054x; 1.0843x over previous
//
#include <hip/hip_runtime.h>

#define C 128

typedef __attribute__((ext_vector_type(8))) short short8v;
typedef __attribute__((ext_vector_type(4))) float float4v;

__device__ __forceinline__ ushort f2bf(float f) {
  union { float f; uint u; } v; v.f = f;
  uint u = v.u;
  return (ushort)((u + 0x7FFF + ((u >> 16) & 1)) >> 16);  // RNE
}
__device__ __forceinline__ float bf2f(ushort s) {
  union { uint u; float f; } v; v.u = ((uint)s) << 16; return v.f;
}

// LDS swizzles: row-stride 128 shorts (16 chunks of 8) / 64 shorts (8 chunks)
__device__ __forceinline__ short* swz(short* base, int row, int chunk) {
  return base + row * 128 + ((chunk ^ (row & 15)) << 3);
}
__device__ __forceinline__ short* swz8(short* base, int row, int chunk) {
  return base + row * 64 + ((chunk ^ (row & 7)) << 3);
}

// ---------------- degree count ------------------------------------------
__global__ void k_degree(const int* __restrict__ col, int* __restrict__ cnt, int E) {
  int e = blockIdx.x * blockDim.x + threadIdx.x;
  if (e < E) atomicAdd(&cnt[col[e]], 1);
}

// ---------------- single-block scan: deg -> dis, indptr, cursor --------
__global__ void k_scan(const int* __restrict__ cnt, float* __restrict__ dis,
                       int* __restrict__ indptr, int* __restrict__ cursor, int N) {
  __shared__ int sb[1024];
  int t = threadIdx.x;
  int chunk = (N + 1023) >> 10;
  int lo = t * chunk, hi = min(lo + chunk, N);
  int sum = 0;
  for (int i = lo; i < hi; ++i) sum += cnt[i];
  sb[t] = sum;
  __syncthreads();
  for (int off = 1; off < 1024; off <<= 1) {
    int v = (t >= off) ? sb[t - off] : 0;
    __syncthreads();
    sb[t] += v;
    __syncthreads();
  }
  int run = sb[t] - sum;
  for (int i = lo; i < hi; ++i) {
    indptr[i] = run; cursor[i] = run;
    dis[i] = rsqrtf((float)(cnt[i] + 1));
    run += cnt[i];
  }
  if (lo < N && hi == N) indptr[N] = run;
}

// ---------------- CSR fill ----------------------------------------------
__global__ void k_csrfill(const int* __restrict__ row, const int* __restrict__ col,
                          const float* __restrict__ dis, int* __restrict__ cursor,
                          int* __restrict__ esrc, float* __restrict__ enorm, int E) {
  int e = blockIdx.x * blockDim.x + threadIdx.x;
  if (e >= E) return;
  int r = row[e], c = col[e];
  int pos = atomicAdd(&cursor[c], 1);
  esrc[pos] = r;
  enorm[pos] = dis[r] * dis[c];
}

// ---------------- W1^T -> bf16 (fc1, hi only) ---------------------------
__global__ void k_prepw(const float* __restrict__ W1, ushort* __restrict__ W1t) {
  int idx = blockIdx.x * 256 + threadIdx.x;  // 16384
  int n = idx >> 7, k = idx & 127;
  W1t[idx] = f2bf(W1[k * C + n]);
}

// ---------------- conv/fc0 W^T -> bf16 hi/lo (10 matrices) --------------
__global__ void k_prepw2(const float* __restrict__ convs_W,
                         const float* __restrict__ fc0_W,
                         ushort* __restrict__ Wth, ushort* __restrict__ Wtl) {
  int g = blockIdx.x * 256 + threadIdx.x;  // [0, 10*16384)
  int mat = g >> 14, idx = g & 16383;
  int n = idx >> 7, k = idx & 127;
  const float* src = (mat < 8) ? convs_W + ((size_t)mat << 14)
                               : fc0_W + ((size_t)(mat - 8) << 14);
  float v = src[k * C + n];
  ushort h = f2bf(v);
  Wth[g] = h;
  Wtl[g] = f2bf(v - bf2f(h));
}

// ---------------- aggregation: agg[v] = sum norm*h[src] + dis^2*h[v] ----
__global__ __launch_bounds__(256)
void k_agg(const float* __restrict__ h, const int* __restrict__ indptr,
           const int* __restrict__ esrc, const float* __restrict__ enorm,
           const float* __restrict__ dis, float* __restrict__ agg, int N) {
  int w = (blockIdx.x * 256 + threadIdx.x) >> 6;
  int lane = threadIdx.x & 63;
  if (w >= N) return;
  int s = indptr[w], e = indptr[w + 1];
  float ax = 0.f, ay = 0.f;
  int i = s;
  for (; i + 4 <= e; i += 4) {  // 4 independent row loads in flight
    int s0 = esrc[i], s1 = esrc[i + 1], s2 = esrc[i + 2], s3 = esrc[i + 3];
    float n0 = enorm[i], n1 = enorm[i + 1], n2 = enorm[i + 2], n3 = enorm[i + 3];
    float2 h0 = *(const float2*)(h + (size_t)s0 * C + lane * 2);
    float2 h1 = *(const float2*)(h + (size_t)s1 * C + lane * 2);
    float2 h2 = *(const float2*)(h + (size_t)s2 * C + lane * 2);
    float2 h3 = *(const float2*)(h + (size_t)s3 * C + lane * 2);
    ax += n0 * h0.x + n1 * h1.x + n2 * h2.x + n3 * h3.x;
    ay += n0 * h0.y + n1 * h1.y + n2 * h2.y + n3 * h3.y;
  }
  for (; i < e; ++i) {
    int s0 = esrc[i]; float n0 = enorm[i];
    float2 h0 = *(const float2*)(h + (size_t)s0 * C + lane * 2);
    ax += n0 * h0.x; ay += n0 * h0.y;
  }
  float dv = dis[w];
  float2 hs = *(const float2*)(h + (size_t)w * C + lane * 2);
  ax += dv * dv * hs.x; ay += dv * dv * hs.y;
  float2 o; o.x = ax; o.y = ay;
  *(float2*)(agg + (size_t)w * C + lane * 2) = o;
}

// ---------------- MFMA GEMM: out[M,128] = op(A[M,128] @ W) --------------
// A fp32 -> hi/lo bf16 in LDS (swizzled); W^T pre-transposed bf16 hi/lo in
// global, staged in two k-halves. 3-term hi/lo product -> fp32-equivalent.
// LDS = 32K(A) + 32K(Whalf) = 64KB -> 2 blocks/CU.
__global__ __launch_bounds__(256, 2)
void k_gemm_mfma(const float* __restrict__ A, const ushort* __restrict__ Wth,
                 const ushort* __restrict__ Wtl, const float* __restrict__ bias,
                 const float* __restrict__ skip, float* __restrict__ out,
                 int M, int relu) {
  __shared__ __align__(16) short Ah[64 * 128];
  __shared__ __align__(16) short Al[64 * 128];
  __shared__ __align__(16) short Wh[128 * 64];
  __shared__ __align__(16) short Wl[128 * 64];
  int t = threadIdx.x;
  int r0 = blockIdx.x * 64;
  // stage A -> hi/lo bf16, swizzled
  {
    int rl = t >> 2, p = t & 3;
    int r = r0 + rl;
    const float* Ar = A + (size_t)r * C + p * 32;
#pragma unroll
    for (int i = 0; i < 4; ++i) {
      float v[8];
      if (r < M) {
        float4 a0 = *(const float4*)(Ar + 8 * i);
        float4 a1 = *(const float4*)(Ar + 8 * i + 4);
        v[0] = a0.x; v[1] = a0.y; v[2] = a0.z; v[3] = a0.w;
        v[4] = a1.x; v[5] = a1.y; v[6] = a1.z; v[7] = a1.w;
      } else {
#pragma unroll
        for (int j = 0; j < 8; ++j) v[j] = 0.f;
      }
      short8v hi, lo;
#pragma unroll
      for (int j = 0; j < 8; ++j) {
        ushort h = f2bf(v[j]);
        hi[j] = (short)h;
        lo[j] = (short)f2bf(v[j] - bf2f(h));
      }
      *(short8v*)swz(Ah, rl, p * 4 + i) = hi;
      *(short8v*)swz(Al, rl, p * 4 + i) = lo;
    }
  }
  int w = t >> 6, lane = t & 63;
  int m0 = w * 16;
  int lm = lane & 15, lq = lane >> 4;
  float4v acc[8];
#pragma unroll
  for (int j = 0; j < 8; ++j) acc[j] = (float4v){0.f, 0.f, 0.f, 0.f};

  for (int half = 0; half < 2; ++half) {
    __syncthreads();
    // stage W^T half: rows n=0..127, k in [half*64, half*64+64)
    {
#pragma unroll
      for (int i = 0; i < 4; ++i) {
        int g = i * 256 + t;           // chunk id 0..1023
        int n = g >> 3, kc = g & 7;
        size_t off = (size_t)n * 128 + half * 64 + kc * 8;
        *(short8v*)swz8(Wh, n, kc) = *(const short8v*)(Wth + off);
        *(short8v*)swz8(Wl, n, kc) = *(const short8v*)(Wtl + off);
      }
    }
    __syncthreads();
#pragma unroll
    for (int kk = 0; kk < 2; ++kk) {
      int ach = (half * 2 + kk) * 4 + lq;  // A chunk 0..15
      int wch = kk * 4 + lq;               // W-half chunk 0..7
      short8v ah = *(const short8v*)swz(Ah, m0 + lm, ach);
      short8v al = *(const short8v*)swz(Al, m0 + lm, ach);
#pragma unroll
      for (int j = 0; j < 8; ++j) {
        short8v bh = *(const short8v*)swz8(Wh, j * 16 + lm, wch);
        short8v bl = *(const short8v*)swz8(Wl, j * 16 + lm, wch);
        acc[j] = __builtin_amdgcn_mfma_f32_16x16x32_bf16(ah, bh, acc[j], 0, 0, 0);
        acc[j] = __builtin_amdgcn_mfma_f32_16x16x32_bf16(al, bh, acc[j], 0, 0, 0);
        acc[j] = __builtin_amdgcn_mfma_f32_16x16x32_bf16(ah, bl, acc[j], 0, 0, 0);
      }
    }
  }
  // epilogue: D row = lq*4+r, col = j*16+lm
#pragma unroll
  for (int j = 0; j < 8; ++j) {
    int n = j * 16 + lm;
    float bv = bias ? bias[n] : 0.f;
#pragma unroll
    for (int r = 0; r < 4; ++r) {
      int m = r0 + m0 + lq * 4 + r;
      if (m >= M) continue;
      float v = acc[j][r] + bv;
      if (skip) v += skip[(size_t)m * C + n];
      if (relu) v = fmaxf(v, 0.f);
      out[(size_t)m * C + n] = v;
    }
  }
}

// ---------------- fused edge MLP, MFMA fc1, hi/lo split e1 ---------------
__global__ __launch_bounds__(256, 2)
void k_edge(const float* __restrict__ P, const float* __restrict__ Q,
            const int* __restrict__ row, const int* __restrict__ col,
            const ushort* __restrict__ W1t, const float* __restrict__ b1,
            const float* __restrict__ w2, const float* __restrict__ b2,
            float* __restrict__ out, int E) {
  __shared__ __align__(16) short EtH[64 * 128];
  __shared__ __align__(16) short EtL[64 * 128];
  __shared__ __align__(16) short Wl[128 * 128];
  int t = threadIdx.x;
  int e0 = blockIdx.x * 64;
  {
    int el = t >> 2, p = t & 3;
    int e = e0 + el;
    if (e >= E) e = E - 1;
    int r = row[e], c = col[e];
    const float* Pp = P + (size_t)r * C + p * 32;
    const float* Qp = Q + (size_t)c * C + p * 32;
#pragma unroll
    for (int i = 0; i < 4; ++i) {
      float4 a0 = *(const float4*)(Pp + 8 * i);
      float4 a1 = *(const float4*)(Pp + 8 * i + 4);
      float4 b0 = *(const float4*)(Qp + 8 * i);
      float4 b1v4 = *(const float4*)(Qp + 8 * i + 4);
      float v[8] = {a0.x + b0.x, a0.y + b0.y, a0.z + b0.z, a0.w + b0.w,
                    a1.x + b1v4.x, a1.y + b1v4.y, a1.z + b1v4.z, a1.w + b1v4.w};
      short8v hi, lo;
#pragma unroll
      for (int j = 0; j < 8; ++j) {
        float f = fmaxf(v[j], 0.f);
        ushort h = f2bf(f);
        hi[j] = (short)h;
        lo[j] = (short)f2bf(f - bf2f(h));
      }
      *(short8v*)swz(EtH, el, p * 4 + i) = hi;
      *(short8v*)swz(EtL, el, p * 4 + i) = lo;
    }
  }
  {
#pragma unroll
    for (int i = 0; i < 8; ++i) {
      int g = i * 256 + t;
      int r = g >> 4, c = g & 15;
      short8v wv = *(const short8v*)(W1t + g * 8);
      *(short8v*)swz(Wl, r, c) = wv;
    }
  }
  __syncthreads();

  int w = t >> 6, lane = t & 63;
  int m0 = w * 16;
  int lm = lane & 15, lq = lane >> 4;
  float4v acc[8];
#pragma unroll
  for (int j = 0; j < 8; ++j) acc[j] = (float4v){0.f, 0.f, 0.f, 0.f};

#pragma unroll
  for (int kk = 0; kk < 4; ++kk) {
    int ch = kk * 4 + lq;
    short8v ah = *(const short8v*)swz(EtH, m0 + lm, ch);
    short8v al = *(const short8v*)swz(EtL, m0 + lm, ch);
#pragma unroll
    for (int j = 0; j < 8; ++j) {
      short8v b = *(const short8v*)swz(Wl, j * 16 + lm, ch);
      acc[j] = __builtin_amdgcn_mfma_f32_16x16x32_bf16(ah, b, acc[j], 0, 0, 0);
      acc[j] = __builtin_amdgcn_mfma_f32_16x16x32_bf16(al, b, acc[j], 0, 0, 0);
    }
  }

  float partv[4] = {0.f, 0.f, 0.f, 0.f};
#pragma unroll
  for (int j = 0; j < 8; ++j) {
    int n = j * 16 + lm;
    float b1v = b1[n], w2v = w2[n];
#pragma unroll
    for (int r = 0; r < 4; ++r) {
      float e2 = fmaxf(acc[j][r] + b1v, 0.f);
      partv[r] = fmaf(e2, w2v, partv[r]);
    }
  }
#pragma unroll
  for (int off = 1; off < 16; off <<= 1) {
#pragma unroll
    for (int r = 0; r < 4; ++r) partv[r] += __shfl_xor(partv[r], off, 64);
  }
  if (lm == 0) {
    float bb = b2[0];
#pragma unroll
    for (int r = 0; r < 4; ++r) {
      int e = e0 + m0 + lq * 4 + r;
      if (e < E) out[e] = partv[r] + bb;
    }
  }
}

// ---------------- host ---------------------------------------------------
extern "C" void kernel_launch(void* const* d_in, const int* in_sizes, int n_in,
                              void* d_out, int out_size, void* d_ws, size_t ws_size,
                              hipStream_t stream) {
  const float* x       = (const float*)d_in[0];
  const int*   ei      = (const int*)d_in[1];
  const float* convs_W = (const float*)d_in[2];
  const float* convs_b = (const float*)d_in[3];
  const float* fc0_W   = (const float*)d_in[4];
  const float* fc0_b   = (const float*)d_in[5];
  const float* fc1_W   = (const float*)d_in[6];
  const float* fc1_b   = (const float*)d_in[7];
  const float* fc2_W   = (const float*)d_in[8];
  const float* fc2_b   = (const float*)d_in[9];
  float* out = (float*)d_out;

  const int N = in_sizes[0] / C;        // 50000
  const int E = in_sizes[1] / 2;        // 1600000
  const int L = in_sizes[2] / (C * C);  // 8
  const int* row = ei;
  const int* col = ei + E;

  char* wp = (char*)d_ws;
  auto carve = [&](size_t bytes) {
    char* p = wp; wp += (bytes + 255) & ~(size_t)255; return p;
  };
  int*    cnt    = (int*)carve((size_t)N * 4);
  int*    indptr = (int*)carve((size_t)(N + 1) * 4);
  int*    cursor = (int*)carve((size_t)N * 4);
  float*  dis    = (float*)carve((size_t)N * 4);
  int*    esrc   = (int*)carve((size_t)E * 4);
  float*  enorm  = (float*)carve((size_t)E * 4);
  ushort* W1t    = (ushort*)carve((size_t)C * C * 2);
  ushort* Wth    = (ushort*)carve((size_t)10 * C * C * 2);
  ushort* Wtl    = (ushort*)carve((size_t)10 * C * C * 2);
  float*  big0   = (float*)carve((size_t)N * C * 4);
  float*  big1   = (float*)carve((size_t)N * C * 4);
  float*  big2   = (float*)carve((size_t)N * C * 4);

  hipMemsetAsync(cnt, 0, (size_t)N * 4, stream);
  k_degree<<<(E + 255) / 256, 256, 0, stream>>>(col, cnt, E);
  k_scan<<<1, 1024, 0, stream>>>(cnt, dis, indptr, cursor, N);
  k_csrfill<<<(E + 255) / 256, 256, 0, stream>>>(row, col, dis, cursor, esrc, enorm, E);
  k_prepw<<<C * C / 256, 256, 0, stream>>>(fc1_W, W1t);
  k_prepw2<<<10 * C * C / 256, 256, 0, stream>>>(convs_W, fc0_W, Wth, Wtl);

  int aggBlocks  = (N * 64 + 255) / 256;
  int gemmBlocks = (N + 63) / 64;
  const int MSZ = C * C;

  // layer 0 (no skip)
  k_agg<<<aggBlocks, 256, 0, stream>>>(x, indptr, esrc, enorm, dis, big1, N);
  k_gemm_mfma<<<gemmBlocks, 256, 0, stream>>>(big1, Wth, Wtl, convs_b, nullptr,
                                              big0, N, 1);
  float* hcur = big0; float* fA = big1; float* fB = big2;
  for (int l = 1; l < L; ++l) {
    k_agg<<<aggBlocks, 256, 0, stream>>>(hcur, indptr, esrc, enorm, dis, fA, N);
    k_gemm_mfma<<<gemmBlocks, 256, 0, stream>>>(fA, Wth + (size_t)l * MSZ,
                                                Wtl + (size_t)l * MSZ,
                                                convs_b + (size_t)l * C, hcur,
                                                fB, N, 1);
    float* tmp = hcur; hcur = fB; fB = tmp;
  }
  // edge MLP: P = h@fc0_W[:128], Q = h@fc0_W[128:] + b0
  float* Pm = fA; float* Qm = fB;
  k_gemm_mfma<<<gemmBlocks, 256, 0, stream>>>(hcur, Wth + (size_t)8 * MSZ,
                                              Wtl + (size_t)8 * MSZ, nullptr,
                                              nullptr, Pm, N, 0);
  k_gemm_mfma<<<gemmBlocks, 256, 0, stream>>>(hcur, Wth + (size_t)9 * MSZ,
                                              Wtl + (size_t)9 * MSZ, fc0_b,
                                              nullptr, Qm, N, 0);
  k_edge<<<(E + 63) / 64, 256, 0, stream>>>(Pm, Qm, row, col, W1t, fc1_b,
                                            fc2_W, fc2_b, out, E);
}